// Round 5
// baseline (326.807 us; speedup 1.0000x reference)
//
#include <hip/hip_runtime.h>
#include <hip/hip_bf16.h>
#include <stdint.h>

// Problem constants (MultiHeadAttention: B=2, S=2048, H=16, Dk=Dv=64, Dm=1024)
#define BATCH 2
#define SEQ   2048
#define NH    16
#define DH    64
#define DM    1024
#define MR    (BATCH * SEQ)   // 4096 rows

typedef __bf16 bf16_t;
typedef bf16_t bf16x4 __attribute__((ext_vector_type(4)));
typedef bf16_t bf16x8 __attribute__((ext_vector_type(8)));
typedef float  f32x4  __attribute__((ext_vector_type(4)));

typedef const __attribute__((address_space(1))) void* gas_t;
typedef       __attribute__((address_space(3))) void* las_t;

__device__ __forceinline__ void gload16(const void* g, void* l) {
  __builtin_amdgcn_global_load_lds((gas_t)g, (las_t)l, 16, 0, 0);
}

__device__ __forceinline__ float fast_exp2(float x) {
#if __has_builtin(__builtin_amdgcn_exp2f)
  return __builtin_amdgcn_exp2f(x);
#else
  float r; asm volatile("v_exp_f32 %0, %1\n\ts_nop 1" : "=v"(r) : "v"(x)); return r;
#endif
}

// ---------------- fp32 -> bf16 elementwise ----------------
__global__ __launch_bounds__(256) void cvt_kernel(const float* __restrict__ x,
                                                  bf16_t* __restrict__ y, int n) {
  int i = (blockIdx.x * 256 + threadIdx.x) * 8;
  if (i + 8 <= n) {
    float4 a = *(const float4*)(x + i);
    float4 b = *(const float4*)(x + i + 4);
    bf16x8 o;
    o[0] = (bf16_t)a.x; o[1] = (bf16_t)a.y; o[2] = (bf16_t)a.z; o[3] = (bf16_t)a.w;
    o[4] = (bf16_t)b.x; o[5] = (bf16_t)b.y; o[6] = (bf16_t)b.z; o[7] = (bf16_t)b.w;
    *(bf16x8*)(y + i) = o;
  }
}

// ---------------- W (KxN f32) -> Wt (NxK bf16), tiled transpose ----------------
__global__ __launch_bounds__(256) void wtrans_kernel(const float* __restrict__ W,
                                                     bf16_t* __restrict__ Wt) {
  __shared__ bf16_t t[64][65];
  const int c0 = blockIdx.x * 64, r0 = blockIdx.y * 64;
  const int tid = threadIdx.x;
  const int r = tid >> 2, cc = (tid & 3) * 16;
  const float* src = W + (size_t)(r0 + r) * DM + c0 + cc;
#pragma unroll
  for (int i = 0; i < 16; ++i) t[r][cc + i] = (bf16_t)src[i];
  __syncthreads();
  bf16_t* dst = Wt + (size_t)(c0 + r) * DM + r0 + cc;
#pragma unroll
  for (int i = 0; i < 16; ++i) dst[i] = t[cc + i][r];
}

// ---------------- v (MR x DM) -> vT (per (b,h): DH x SEQ) ----------------
__global__ __launch_bounds__(256) void vtrans_kernel(const bf16_t* __restrict__ v,
                                                     bf16_t* __restrict__ vT) {
  __shared__ bf16_t t[64][65];
  const int s0 = blockIdx.x * 64;
  const int h = blockIdx.y, b = blockIdx.z;
  const int tid = threadIdx.x;
  const int r = tid >> 2, cc = (tid & 3) * 16;
  const bf16_t* src = v + (size_t)(b * SEQ + s0 + r) * DM + h * DH + cc;
#pragma unroll
  for (int i = 0; i < 16; ++i) t[r][cc + i] = src[i];
  __syncthreads();
  bf16_t* dst = vT + (size_t)((b * NH + h) * DH + r) * SEQ + s0 + cc;
#pragma unroll
  for (int i = 0; i < 16; ++i) dst[i] = t[cc + i][r];
}

// ---------------- GEMM: C(MxN) = (A(MxK) @ Bt(NxK)^T + bias) * scale -----------
// 64x128 tile (512 blocks = 2/CU for M=4096,N=1024), BK=64, 4 waves (2x2),
// wave = 32m x 64n. global_load_lds w=16, XOR-swizzled LDS rows.
template <int OUT_BF16>
__global__ __launch_bounds__(256) void gemm_kernel(const bf16_t* __restrict__ A,
                                                   const bf16_t* __restrict__ Bt,
                                                   const float* __restrict__ bias,
                                                   float scale,
                                                   void* __restrict__ Cv,
                                                   int K, int N) {
  __shared__ __attribute__((aligned(16))) bf16_t As[64 * 64];    // 8 KB
  __shared__ __attribute__((aligned(16))) bf16_t Bs[128 * 64];   // 16 KB
  const int m0 = blockIdx.x * 64, n0 = blockIdx.y * 128;
  const int tid = threadIdx.x;
  const int wave = tid >> 6, lane = tid & 63;
  const int lm = lane & 15, lg = lane >> 4;
  const int wr = wave >> 1, wc = wave & 1;
  f32x4 acc[2][4];
#pragma unroll
  for (int a = 0; a < 2; ++a)
#pragma unroll
    for (int bb = 0; bb < 4; ++bb) acc[a][bb] = (f32x4){0.f, 0.f, 0.f, 0.f};

  for (int k0 = 0; k0 < K; k0 += 64) {
    __syncthreads();
#pragma unroll
    for (int i = 0; i < 2; ++i) {            // A: 512 chunks
      const int c = tid + i * 256;
      const int row = c >> 3, j = c & 7, js = j ^ (row & 7);
      gload16(A + (size_t)(m0 + row) * K + k0 + js * 8,
              As + (size_t)(wave * 64 + i * 256) * 8);
    }
#pragma unroll
    for (int i = 0; i < 4; ++i) {            // B: 1024 chunks
      const int c = tid + i * 256;
      const int row = c >> 3, j = c & 7, js = j ^ (row & 7);
      gload16(Bt + (size_t)(n0 + row) * K + k0 + js * 8,
              Bs + (size_t)(wave * 64 + i * 256) * 8);
    }
    asm volatile("s_waitcnt vmcnt(0)" ::: "memory");
    __syncthreads();
#pragma unroll
    for (int kk = 0; kk < 2; ++kk) {
      bf16x8 af[2], bfr[4];
#pragma unroll
      for (int t = 0; t < 2; ++t) {
        const int ra = wr * 32 + t * 16 + lm;
        af[t] = *(const bf16x8*)((const char*)As + ra * 128 +
                                 ((kk * 64 + lg * 16) ^ ((ra & 7) << 4)));
      }
#pragma unroll
      for (int t = 0; t < 4; ++t) {
        const int rb = wc * 64 + t * 16 + lm;
        bfr[t] = *(const bf16x8*)((const char*)Bs + rb * 128 +
                                  ((kk * 64 + lg * 16) ^ ((rb & 7) << 4)));
      }
#pragma unroll
      for (int mf = 0; mf < 2; ++mf)
#pragma unroll
        for (int nf = 0; nf < 4; ++nf)
          acc[mf][nf] = __builtin_amdgcn_mfma_f32_16x16x32_bf16(af[mf], bfr[nf],
                                                                acc[mf][nf], 0, 0, 0);
    }
  }
#pragma unroll
  for (int mf = 0; mf < 2; ++mf)
#pragma unroll
    for (int nf = 0; nf < 4; ++nf) {
      const int col = n0 + wc * 64 + nf * 16 + lm;
      const float bv = bias[col];
#pragma unroll
      for (int i = 0; i < 4; ++i) {
        const int row = m0 + wr * 32 + mf * 16 + lg * 4 + i;
        const float val = (acc[mf][nf][i] + bv) * scale;
        if (OUT_BF16) ((bf16_t*)Cv)[(size_t)row * N + col] = (bf16_t)val;
        else          ((float*)Cv)[(size_t)row * N + col] = val;
      }
    }
}

// ---------------- flash attention v2: swapped-QK lane-local softmax ------------
// Grid 1024 (XCD-swizzled) = 4 blocks/CU; 4 waves/block; wave owns 16 q-rows.
// sc = mfma(K_frag, Q_frag): D col=lane&15=q, row=lg*4+i=k -> each lane holds
// 16 k-values of ITS q-row (lane&15). Row max/sum = 15 lane-local ops +
// 2 shfl_xor (lg groups). alpha/l broadcast to acc rows via 4 shfl.
// P -> LDS as 4 ds_write_b64, read back as A-frags (2 ds_read_b128). No barriers.
__global__ __launch_bounds__(256, 4) void flash_kernel(const bf16_t* __restrict__ q,
                                                       const bf16_t* __restrict__ k,
                                                       const bf16_t* __restrict__ vT,
                                                       bf16_t* __restrict__ o) {
  __shared__ __attribute__((aligned(16))) bf16_t Ps[4 * 16 * 64];  // 8 KB
  const int wg = blockIdx.x;
  const int swz = (wg & 7) * 128 + (wg >> 3);   // 1024 wgs, 128/XCD
  const int qt = swz & 31, h = (swz >> 5) & 15, b = swz >> 9;
  const int tid = threadIdx.x;
  const int wave = tid >> 6, lane = tid & 63;
  const int lm = lane & 15, lg = lane >> 4;
  char* PsW = (char*)Ps + wave * 2048;

  const bf16_t* qb = q + (size_t)(b * SEQ + qt * 64 + wave * 16) * DM + h * DH;
  const bf16_t* kb = k + (size_t)b * SEQ * DM + h * DH;
  const bf16_t* vb = vT + (size_t)(b * NH + h) * DH * SEQ;

  bf16x8 qf[2];
#pragma unroll
  for (int kk = 0; kk < 2; ++kk)
    qf[kk] = *(const bf16x8*)(qb + (size_t)lm * DM + kk * 32 + lg * 8);

  f32x4 acc[4];
#pragma unroll
  for (int nf = 0; nf < 4; ++nf) acc[nf] = (f32x4){0.f, 0.f, 0.f, 0.f};
  float mrun = -1e30f, lrun = 0.f;

  for (int t = 0; t < SEQ / 64; ++t) {
    // ---- K fragments (L2-direct) + swapped QK^T ----
    bf16x8 kf[2][4];
#pragma unroll
    for (int kk = 0; kk < 2; ++kk)
#pragma unroll
      for (int nf = 0; nf < 4; ++nf)
        kf[kk][nf] = *(const bf16x8*)(kb + (size_t)(t * 64 + nf * 16 + lm) * DM +
                                      kk * 32 + lg * 8);
    f32x4 sc[4];
#pragma unroll
    for (int nf = 0; nf < 4; ++nf) sc[nf] = (f32x4){0.f, 0.f, 0.f, 0.f};
#pragma unroll
    for (int kk = 0; kk < 2; ++kk)
#pragma unroll
      for (int nf = 0; nf < 4; ++nf)
        sc[nf] = __builtin_amdgcn_mfma_f32_16x16x32_bf16(kf[kk][nf], qf[kk],
                                                         sc[nf], 0, 0, 0);
    // ---- V fragments issued early (latency hidden under softmax) ----
    bf16x8 vf[2][4];
#pragma unroll
    for (int kk = 0; kk < 2; ++kk)
#pragma unroll
      for (int nf = 0; nf < 4; ++nf)
        vf[kk][nf] = *(const bf16x8*)(vb + (size_t)(nf * 16 + lm) * SEQ +
                                      t * 64 + kk * 32 + lg * 8);

    // ---- lane-local online softmax (q pre-scaled by 0.125*log2e) ----
    float ml = fmaxf(
        fmaxf(fmaxf(fmaxf(sc[0][0], sc[0][1]), fmaxf(sc[0][2], sc[0][3])),
              fmaxf(fmaxf(sc[1][0], sc[1][1]), fmaxf(sc[1][2], sc[1][3]))),
        fmaxf(fmaxf(fmaxf(sc[2][0], sc[2][1]), fmaxf(sc[2][2], sc[2][3])),
              fmaxf(fmaxf(sc[3][0], sc[3][1]), fmaxf(sc[3][2], sc[3][3]))));
    ml = fmaxf(ml, __shfl_xor(ml, 16));
    ml = fmaxf(ml, __shfl_xor(ml, 32));
    const float mn = fmaxf(mrun, ml);
    const float alpha = fast_exp2(mrun - mn);
    mrun = mn;
#pragma unroll
    for (int nf = 0; nf < 4; ++nf)
#pragma unroll
      for (int i = 0; i < 4; ++i) sc[nf][i] = fast_exp2(sc[nf][i] - mn);
    float s = ((sc[0][0] + sc[0][1]) + (sc[0][2] + sc[0][3])) +
              ((sc[1][0] + sc[1][1]) + (sc[1][2] + sc[1][3])) +
              ((sc[2][0] + sc[2][1]) + (sc[2][2] + sc[2][3])) +
              ((sc[3][0] + sc[3][1]) + (sc[3][2] + sc[3][3]));
    s += __shfl_xor(s, 16);
    s += __shfl_xor(s, 32);
    lrun = lrun * alpha + s;

    // ---- rescale acc: alpha for q-row lg*4+i lives at lane (lg<<4)|(lg*4+i) ----
    float ai[4];
#pragma unroll
    for (int i = 0; i < 4; ++i) ai[i] = __shfl(alpha, (lane & 48) | (lg * 4 + i));
#pragma unroll
    for (int nf = 0; nf < 4; ++nf)
#pragma unroll
      for (int i = 0; i < 4; ++i) acc[nf][i] *= ai[i];

    // ---- P -> LDS (row = q = lm, 4 consecutive k per write) ----
#pragma unroll
    for (int nf = 0; nf < 4; ++nf) {
      bf16x4 pw;
      pw[0] = (bf16_t)sc[nf][0]; pw[1] = (bf16_t)sc[nf][1];
      pw[2] = (bf16_t)sc[nf][2]; pw[3] = (bf16_t)sc[nf][3];
      *(bf16x4*)(PsW + lm * 128 + ((nf * 32 + lg * 8) ^ ((lm & 7) << 4))) = pw;
    }
    // ---- PV (same-wave LDS RAW; no barrier) ----
#pragma unroll
    for (int kk = 0; kk < 2; ++kk) {
      bf16x8 pf = *(const bf16x8*)(PsW + lm * 128 +
                                   ((kk * 64 + lg * 16) ^ ((lm & 7) << 4)));
#pragma unroll
      for (int nf = 0; nf < 4; ++nf)
        acc[nf] = __builtin_amdgcn_mfma_f32_16x16x32_bf16(pf, vf[kk][nf],
                                                          acc[nf], 0, 0, 0);
    }
  }

  // ---- epilogue ----
  const float inv = __builtin_amdgcn_rcpf(lrun);
  float li[4];
#pragma unroll
  for (int i = 0; i < 4; ++i) li[i] = __shfl(inv, (lane & 48) | (lg * 4 + i));
#pragma unroll
  for (int i = 0; i < 4; ++i) {
    const int row = b * SEQ + qt * 64 + wave * 16 + lg * 4 + i;
#pragma unroll
    for (int nf = 0; nf < 4; ++nf) {
      const int col = h * DH + nf * 16 + lm;
      o[(size_t)row * DM + col] = (bf16_t)(acc[nf][i] * li[i]);
    }
  }
}

extern "C" void kernel_launch(void* const* d_in, const int* in_sizes, int n_in,
                              void* d_out, int out_size, void* d_ws, size_t ws_size,
                              hipStream_t stream) {
  (void)in_sizes; (void)n_in; (void)out_size; (void)ws_size;
  const float* Q  = (const float*)d_in[0];
  const float* Kx = (const float*)d_in[1];
  const float* V  = (const float*)d_in[2];
  const float* WQ = (const float*)d_in[3];
  const float* bQ = (const float*)d_in[4];
  const float* WK = (const float*)d_in[5];
  const float* bK = (const float*)d_in[6];
  const float* WV = (const float*)d_in[7];
  const float* bV = (const float*)d_in[8];
  const float* WO = (const float*)d_in[9];
  const float* bO = (const float*)d_in[10];

  const size_t MS  = (size_t)MR * DM;   // 4M elements
  const size_t WSZ = (size_t)DM * DM;   // 1M elements
  bf16_t* ws  = (bf16_t*)d_ws;
  bf16_t* Qb  = ws;
  bf16_t* Kb  = Qb + MS;
  bf16_t* Vb  = Kb + MS;
  bf16_t* WQt = Vb + MS;
  bf16_t* WKt = WQt + WSZ;
  bf16_t* WVt = WKt + WSZ;
  bf16_t* WOt = WVt + WSZ;
  bf16_t* qp  = WOt + WSZ;
  bf16_t* kp  = qp + MS;
  bf16_t* vp  = kp + MS;
  bf16_t* vTb = Qb;   // alias: Qb dead after q projection
  bf16_t* ao  = Kb;   // alias: Kb dead after k projection

  // fold score scale and log2(e) into the q projection -> softmax uses exp2
  const float scale_q = 0.125f * 1.44269504088896340736f;

  cvt_kernel<<<dim3((unsigned)(MS / 2048)), 256, 0, stream>>>(Q,  Qb, (int)MS);
  cvt_kernel<<<dim3((unsigned)(MS / 2048)), 256, 0, stream>>>(Kx, Kb, (int)MS);
  cvt_kernel<<<dim3((unsigned)(MS / 2048)), 256, 0, stream>>>(V,  Vb, (int)MS);
  wtrans_kernel<<<dim3(16, 16), 256, 0, stream>>>(WQ, WQt);
  wtrans_kernel<<<dim3(16, 16), 256, 0, stream>>>(WK, WKt);
  wtrans_kernel<<<dim3(16, 16), 256, 0, stream>>>(WV, WVt);
  wtrans_kernel<<<dim3(16, 16), 256, 0, stream>>>(WO, WOt);

  gemm_kernel<1><<<dim3(MR / 64, DM / 128), 256, 0, stream>>>(Qb, WQt, bQ, scale_q, qp, DM, DM);
  gemm_kernel<1><<<dim3(MR / 64, DM / 128), 256, 0, stream>>>(Kb, WKt, bK, 1.0f, kp, DM, DM);
  gemm_kernel<1><<<dim3(MR / 64, DM / 128), 256, 0, stream>>>(Vb, WVt, bV, 1.0f, vp, DM, DM);

  vtrans_kernel<<<dim3(SEQ / 64, NH, BATCH), 256, 0, stream>>>(vp, vTb);
  flash_kernel<<<dim3(1024), 256, 0, stream>>>(qp, kp, vTb, ao);
  gemm_kernel<0><<<dim3(MR / 64, DM / 128), 256, 0, stream>>>(ao, WOt, bO, 1.0f, d_out, DM, DM);
}

// Round 6
// 159.143 us; speedup vs baseline: 2.0535x; 2.0535x over previous
//
#include <hip/hip_runtime.h>
#include <hip/hip_bf16.h>
#include <stdint.h>

// Problem constants (MultiHeadAttention: B=2, S=2048, H=16, Dk=Dv=64, Dm=1024)
#define BATCH 2
#define SEQ   2048
#define NH    16
#define DH    64
#define DM    1024
#define MR    (BATCH * SEQ)   // 4096 rows

typedef __bf16 bf16_t;
typedef bf16_t bf16x4 __attribute__((ext_vector_type(4)));
typedef bf16_t bf16x8 __attribute__((ext_vector_type(8)));
typedef float  f32x4  __attribute__((ext_vector_type(4)));

typedef const __attribute__((address_space(1))) void* gas_t;
typedef       __attribute__((address_space(3))) void* las_t;

__device__ __forceinline__ void gload16(const void* g, void* l) {
  __builtin_amdgcn_global_load_lds((gas_t)g, (las_t)l, 16, 0, 0);
}

__device__ __forceinline__ float fast_exp2(float x) {
#if __has_builtin(__builtin_amdgcn_exp2f)
  return __builtin_amdgcn_exp2f(x);
#else
  float r; asm volatile("v_exp_f32 %0, %1\n\ts_nop 1" : "=v"(r) : "v"(x)); return r;
#endif
}

// ---------------- fp32 -> bf16 elementwise ----------------
__global__ __launch_bounds__(256) void cvt_kernel(const float* __restrict__ x,
                                                  bf16_t* __restrict__ y, int n) {
  int i = (blockIdx.x * 256 + threadIdx.x) * 8;
  if (i + 8 <= n) {
    float4 a = *(const float4*)(x + i);
    float4 b = *(const float4*)(x + i + 4);
    bf16x8 o;
    o[0] = (bf16_t)a.x; o[1] = (bf16_t)a.y; o[2] = (bf16_t)a.z; o[3] = (bf16_t)a.w;
    o[4] = (bf16_t)b.x; o[5] = (bf16_t)b.y; o[6] = (bf16_t)b.z; o[7] = (bf16_t)b.w;
    *(bf16x8*)(y + i) = o;
  }
}

// ---------------- W (KxN f32) -> Wt (NxK bf16), tiled transpose ----------------
__global__ __launch_bounds__(256) void wtrans_kernel(const float* __restrict__ W,
                                                     bf16_t* __restrict__ Wt) {
  __shared__ bf16_t t[64][65];
  const int c0 = blockIdx.x * 64, r0 = blockIdx.y * 64;
  const int tid = threadIdx.x;
  const int r = tid >> 2, cc = (tid & 3) * 16;
  const float* src = W + (size_t)(r0 + r) * DM + c0 + cc;
#pragma unroll
  for (int i = 0; i < 16; ++i) t[r][cc + i] = (bf16_t)src[i];
  __syncthreads();
  bf16_t* dst = Wt + (size_t)(c0 + r) * DM + r0 + cc;
#pragma unroll
  for (int i = 0; i < 16; ++i) dst[i] = t[cc + i][r];
}

// ---------------- v (MR x DM) -> vT (per (b,h): DH x SEQ) ----------------
__global__ __launch_bounds__(256) void vtrans_kernel(const bf16_t* __restrict__ v,
                                                     bf16_t* __restrict__ vT) {
  __shared__ bf16_t t[64][65];
  const int s0 = blockIdx.x * 64;
  const int h = blockIdx.y, b = blockIdx.z;
  const int tid = threadIdx.x;
  const int r = tid >> 2, cc = (tid & 3) * 16;
  const bf16_t* src = v + (size_t)(b * SEQ + s0 + r) * DM + h * DH + cc;
#pragma unroll
  for (int i = 0; i < 16; ++i) t[r][cc + i] = src[i];
  __syncthreads();
  bf16_t* dst = vT + (size_t)((b * NH + h) * DH + r) * SEQ + s0 + cc;
#pragma unroll
  for (int i = 0; i < 16; ++i) dst[i] = t[cc + i][r];
}

// ---------------- GEMM: C(MxN) = (A(MxK) @ Bt(NxK)^T + bias) * scale -----------
// 64x128 tile (512 blocks = 2/CU for M=4096,N=1024), BK=64, 4 waves (2x2),
// wave = 32m x 64n. global_load_lds w=16, XOR-swizzled LDS rows.
template <int OUT_BF16>
__global__ __launch_bounds__(256) void gemm_kernel(const bf16_t* __restrict__ A,
                                                   const bf16_t* __restrict__ Bt,
                                                   const float* __restrict__ bias,
                                                   float scale,
                                                   void* __restrict__ Cv,
                                                   int K, int N) {
  __shared__ __attribute__((aligned(16))) bf16_t As[64 * 64];    // 8 KB
  __shared__ __attribute__((aligned(16))) bf16_t Bs[128 * 64];   // 16 KB
  const int m0 = blockIdx.x * 64, n0 = blockIdx.y * 128;
  const int tid = threadIdx.x;
  const int wave = tid >> 6, lane = tid & 63;
  const int lm = lane & 15, lg = lane >> 4;
  const int wr = wave >> 1, wc = wave & 1;
  f32x4 acc[2][4];
#pragma unroll
  for (int a = 0; a < 2; ++a)
#pragma unroll
    for (int bb = 0; bb < 4; ++bb) acc[a][bb] = (f32x4){0.f, 0.f, 0.f, 0.f};

  for (int k0 = 0; k0 < K; k0 += 64) {
    __syncthreads();
#pragma unroll
    for (int i = 0; i < 2; ++i) {            // A: 512 chunks
      const int c = tid + i * 256;
      const int row = c >> 3, j = c & 7, js = j ^ (row & 7);
      gload16(A + (size_t)(m0 + row) * K + k0 + js * 8,
              As + (size_t)(wave * 64 + i * 256) * 8);
    }
#pragma unroll
    for (int i = 0; i < 4; ++i) {            // B: 1024 chunks
      const int c = tid + i * 256;
      const int row = c >> 3, j = c & 7, js = j ^ (row & 7);
      gload16(Bt + (size_t)(n0 + row) * K + k0 + js * 8,
              Bs + (size_t)(wave * 64 + i * 256) * 8);
    }
    asm volatile("s_waitcnt vmcnt(0)" ::: "memory");
    __syncthreads();
#pragma unroll
    for (int kk = 0; kk < 2; ++kk) {
      bf16x8 af[2], bfr[4];
#pragma unroll
      for (int t = 0; t < 2; ++t) {
        const int ra = wr * 32 + t * 16 + lm;
        af[t] = *(const bf16x8*)((const char*)As + ra * 128 +
                                 ((kk * 64 + lg * 16) ^ ((ra & 7) << 4)));
      }
#pragma unroll
      for (int t = 0; t < 4; ++t) {
        const int rb = wc * 64 + t * 16 + lm;
        bfr[t] = *(const bf16x8*)((const char*)Bs + rb * 128 +
                                  ((kk * 64 + lg * 16) ^ ((rb & 7) << 4)));
      }
#pragma unroll
      for (int mf = 0; mf < 2; ++mf)
#pragma unroll
        for (int nf = 0; nf < 4; ++nf)
          acc[mf][nf] = __builtin_amdgcn_mfma_f32_16x16x32_bf16(af[mf], bfr[nf],
                                                                acc[mf][nf], 0, 0, 0);
    }
  }
#pragma unroll
  for (int mf = 0; mf < 2; ++mf)
#pragma unroll
    for (int nf = 0; nf < 4; ++nf) {
      const int col = n0 + wc * 64 + nf * 16 + lm;
      const float bv = bias[col];
#pragma unroll
      for (int i = 0; i < 4; ++i) {
        const int row = m0 + wr * 32 + mf * 16 + lg * 4 + i;
        const float val = (acc[mf][nf][i] + bv) * scale;
        if (OUT_BF16) ((bf16_t*)Cv)[(size_t)row * N + col] = (bf16_t)val;
        else          ((float*)Cv)[(size_t)row * N + col] = val;
      }
    }
}

// ---------------- flash attention v3: staged K/V + swapped-QK softmax ----------
// Grid 512 (XCD-swizzled), 8 waves x 16 q-rows = 128 q/block. K/V tiles (64 k)
// staged in LDS via global_load_lds (coalesced), double-buffered, counted
// vmcnt(2) + raw s_barrier (no full drain). Softmax lane-local via swapped QK^T.
__global__ __launch_bounds__(512, 4) void flash_kernel(const bf16_t* __restrict__ q,
                                                       const bf16_t* __restrict__ k,
                                                       const bf16_t* __restrict__ vT,
                                                       bf16_t* __restrict__ o) {
  __shared__ __attribute__((aligned(16))) bf16_t Ks[2][64 * 64];   // 16 KB
  __shared__ __attribute__((aligned(16))) bf16_t Vs[2][64 * 64];   // 16 KB [d][k]
  __shared__ __attribute__((aligned(16))) bf16_t Ps[8][16 * 64];   // 16 KB
  const int wg = blockIdx.x;
  const int swz = (wg & 7) * 64 + (wg >> 3);     // 512 wgs, 64/XCD
  const int qt = swz & 15, h = (swz >> 4) & 15, b = swz >> 8;
  const int tid = threadIdx.x;
  const int wave = tid >> 6, lane = tid & 63;
  const int lm = lane & 15, lg = lane >> 4;
  char* PsW = (char*)(&Ps[wave][0]);

  const bf16_t* qb = q + (size_t)(b * SEQ + qt * 128 + wave * 16) * DM + h * DH;
  // staging: thread tid owns chunk tid (row=tid>>3, 16B col-chunk (tid&7)^swz)
  const int srow = tid >> 3, sjs = (tid & 7) ^ (srow & 7);
  const bf16_t* ksrc = k + (size_t)b * SEQ * DM + h * DH + (size_t)srow * DM + sjs * 8;
  const bf16_t* vsrc = vT + (size_t)(b * NH + h) * DH * SEQ + (size_t)srow * SEQ + sjs * 8;
  bf16_t* kdst0 = &Ks[0][wave * 512];
  bf16_t* kdst1 = &Ks[1][wave * 512];
  bf16_t* vdst0 = &Vs[0][wave * 512];
  bf16_t* vdst1 = &Vs[1][wave * 512];

  bf16x8 qf[2];
#pragma unroll
  for (int kk = 0; kk < 2; ++kk)
    qf[kk] = *(const bf16x8*)(qb + (size_t)lm * DM + kk * 32 + lg * 8);

  f32x4 acc[4];
#pragma unroll
  for (int nf = 0; nf < 4; ++nf) acc[nf] = (f32x4){0.f, 0.f, 0.f, 0.f};
  float mrun = -1e30f, lrun = 0.f;

  // prologue: stage tile 0 into buf 0
  gload16(ksrc, kdst0);
  gload16(vsrc, vdst0);

  const int NT = SEQ / 64;  // 32
  for (int t = 0; t < NT; ++t) {
    const int cur = t & 1;
    asm volatile("" ::: "memory");
    __builtin_amdgcn_s_barrier();        // all waves done reading buf[cur^1]
    if (t + 1 < NT) {
      gload16(ksrc + (size_t)(t + 1) * 64 * DM, cur ? kdst0 : kdst1);
      gload16(vsrc + (t + 1) * 64,              cur ? vdst0 : vdst1);
      asm volatile("s_waitcnt vmcnt(2)" ::: "memory");   // tile t done; t+1 in flight
    } else {
      asm volatile("s_waitcnt vmcnt(0)" ::: "memory");
    }
    __builtin_amdgcn_s_barrier();        // tile t visible to all waves
    asm volatile("" ::: "memory");

    const char* Kb_ = (const char*)&Ks[cur][0];
    const char* Vb_ = (const char*)&Vs[cur][0];

    // ---- swapped QK^T: sc[nf] lane (lm,lg) = S[k=nf*16+lg*4+i][q=lm] ----
    bf16x8 kf[2][4];
#pragma unroll
    for (int kk = 0; kk < 2; ++kk)
#pragma unroll
      for (int nf = 0; nf < 4; ++nf) {
        const int row = nf * 16 + lm;
        kf[kk][nf] = *(const bf16x8*)(Kb_ + row * 128 +
                                      ((kk * 64 + lg * 16) ^ ((row & 7) << 4)));
      }
    f32x4 sc[4];
#pragma unroll
    for (int nf = 0; nf < 4; ++nf) sc[nf] = (f32x4){0.f, 0.f, 0.f, 0.f};
#pragma unroll
    for (int kk = 0; kk < 2; ++kk)
#pragma unroll
      for (int nf = 0; nf < 4; ++nf)
        sc[nf] = __builtin_amdgcn_mfma_f32_16x16x32_bf16(kf[kk][nf], qf[kk],
                                                         sc[nf], 0, 0, 0);

    // ---- lane-local online softmax (q pre-scaled by 0.125*log2e) ----
    float ml = fmaxf(
        fmaxf(fmaxf(fmaxf(sc[0][0], sc[0][1]), fmaxf(sc[0][2], sc[0][3])),
              fmaxf(fmaxf(sc[1][0], sc[1][1]), fmaxf(sc[1][2], sc[1][3]))),
        fmaxf(fmaxf(fmaxf(sc[2][0], sc[2][1]), fmaxf(sc[2][2], sc[2][3])),
              fmaxf(fmaxf(sc[3][0], sc[3][1]), fmaxf(sc[3][2], sc[3][3]))));
    ml = fmaxf(ml, __shfl_xor(ml, 16));
    ml = fmaxf(ml, __shfl_xor(ml, 32));
    const float mn = fmaxf(mrun, ml);
    const float alpha = fast_exp2(mrun - mn);
    mrun = mn;
#pragma unroll
    for (int nf = 0; nf < 4; ++nf)
#pragma unroll
      for (int i = 0; i < 4; ++i) sc[nf][i] = fast_exp2(sc[nf][i] - mn);
    float s = ((sc[0][0] + sc[0][1]) + (sc[0][2] + sc[0][3])) +
              ((sc[1][0] + sc[1][1]) + (sc[1][2] + sc[1][3])) +
              ((sc[2][0] + sc[2][1]) + (sc[2][2] + sc[2][3])) +
              ((sc[3][0] + sc[3][1]) + (sc[3][2] + sc[3][3]));
    s += __shfl_xor(s, 16);
    s += __shfl_xor(s, 32);
    lrun = lrun * alpha + s;

    // ---- rescale acc: alpha for q-row lg*4+i lives at lane (lg<<4)|(lg*4+i) ----
    float ai[4];
#pragma unroll
    for (int i = 0; i < 4; ++i) ai[i] = __shfl(alpha, (lane & 48) | (lg * 4 + i));
#pragma unroll
    for (int nf = 0; nf < 4; ++nf)
#pragma unroll
      for (int i = 0; i < 4; ++i) acc[nf][i] *= ai[i];

    // ---- P -> per-wave LDS (row = q = lm) ----
#pragma unroll
    for (int nf = 0; nf < 4; ++nf) {
      bf16x4 pw;
      pw[0] = (bf16_t)sc[nf][0]; pw[1] = (bf16_t)sc[nf][1];
      pw[2] = (bf16_t)sc[nf][2]; pw[3] = (bf16_t)sc[nf][3];
      *(bf16x4*)(PsW + lm * 128 + ((nf * 32 + lg * 8) ^ ((lm & 7) << 4))) = pw;
    }

    // ---- PV: acc[nf] += P(16q x 64k) @ V(64k x 16d-block nf) ----
#pragma unroll
    for (int kk = 0; kk < 2; ++kk) {
      bf16x8 pf = *(const bf16x8*)(PsW + lm * 128 +
                                   ((kk * 64 + lg * 16) ^ ((lm & 7) << 4)));
      bf16x8 vf[4];
#pragma unroll
      for (int nf = 0; nf < 4; ++nf) {
        const int row = nf * 16 + lm;    // d-row in Vs
        vf[nf] = *(const bf16x8*)(Vb_ + row * 128 +
                                  ((kk * 64 + lg * 16) ^ ((row & 7) << 4)));
      }
#pragma unroll
      for (int nf = 0; nf < 4; ++nf)
        acc[nf] = __builtin_amdgcn_mfma_f32_16x16x32_bf16(pf, vf[nf],
                                                          acc[nf], 0, 0, 0);
    }
  }

  // ---- epilogue: O /= l ----
  const float inv = __builtin_amdgcn_rcpf(lrun);
  float li[4];
#pragma unroll
  for (int i = 0; i < 4; ++i) li[i] = __shfl(inv, (lane & 48) | (lg * 4 + i));
#pragma unroll
  for (int i = 0; i < 4; ++i) {
    const int row = b * SEQ + qt * 128 + wave * 16 + lg * 4 + i;
#pragma unroll
    for (int nf = 0; nf < 4; ++nf) {
      const int col = h * DH + nf * 16 + lm;
      o[(size_t)row * DM + col] = (bf16_t)(acc[nf][i] * li[i]);
    }
  }
}

extern "C" void kernel_launch(void* const* d_in, const int* in_sizes, int n_in,
                              void* d_out, int out_size, void* d_ws, size_t ws_size,
                              hipStream_t stream) {
  (void)in_sizes; (void)n_in; (void)out_size; (void)ws_size;
  const float* Q  = (const float*)d_in[0];
  const float* Kx = (const float*)d_in[1];
  const float* V  = (const float*)d_in[2];
  const float* WQ = (const float*)d_in[3];
  const float* bQ = (const float*)d_in[4];
  const float* WK = (const float*)d_in[5];
  const float* bK = (const float*)d_in[6];
  const float* WV = (const float*)d_in[7];
  const float* bV = (const float*)d_in[8];
  const float* WO = (const float*)d_in[9];
  const float* bO = (const float*)d_in[10];

  const size_t MS  = (size_t)MR * DM;   // 4M elements
  const size_t WSZ = (size_t)DM * DM;   // 1M elements
  bf16_t* ws  = (bf16_t*)d_ws;
  bf16_t* Qb  = ws;
  bf16_t* Kb  = Qb + MS;
  bf16_t* Vb  = Kb + MS;
  bf16_t* WQt = Vb + MS;
  bf16_t* WKt = WQt + WSZ;
  bf16_t* WVt = WKt + WSZ;
  bf16_t* WOt = WVt + WSZ;
  bf16_t* qp  = WOt + WSZ;
  bf16_t* kp  = qp + MS;
  bf16_t* vp  = kp + MS;
  bf16_t* vTb = Qb;   // alias: Qb dead after q projection
  bf16_t* ao  = Kb;   // alias: Kb dead after k projection

  // fold score scale and log2(e) into the q projection -> softmax uses exp2
  const float scale_q = 0.125f * 1.44269504088896340736f;

  cvt_kernel<<<dim3((unsigned)(MS / 2048)), 256, 0, stream>>>(Q,  Qb, (int)MS);
  cvt_kernel<<<dim3((unsigned)(MS / 2048)), 256, 0, stream>>>(Kx, Kb, (int)MS);
  cvt_kernel<<<dim3((unsigned)(MS / 2048)), 256, 0, stream>>>(V,  Vb, (int)MS);
  wtrans_kernel<<<dim3(16, 16), 256, 0, stream>>>(WQ, WQt);
  wtrans_kernel<<<dim3(16, 16), 256, 0, stream>>>(WK, WKt);
  wtrans_kernel<<<dim3(16, 16), 256, 0, stream>>>(WV, WVt);
  wtrans_kernel<<<dim3(16, 16), 256, 0, stream>>>(WO, WOt);

  gemm_kernel<1><<<dim3(MR / 64, DM / 128), 256, 0, stream>>>(Qb, WQt, bQ, scale_q, qp, DM, DM);
  gemm_kernel<1><<<dim3(MR / 64, DM / 128), 256, 0, stream>>>(Kb, WKt, bK, 1.0f, kp, DM, DM);
  gemm_kernel<1><<<dim3(MR / 64, DM / 128), 256, 0, stream>>>(Vb, WVt, bV, 1.0f, vp, DM, DM);

  vtrans_kernel<<<dim3(SEQ / 64, NH, BATCH), 256, 0, stream>>>(vp, vTb);
  flash_kernel<<<dim3(512), 512, 0, stream>>>(qp, kp, vTb, ao);
  gemm_kernel<0><<<dim3(MR / 64, DM / 128), 256, 0, stream>>>(ao, WOt, bO, 1.0f, d_out, DM, DM);
}

// Round 7
// 138.107 us; speedup vs baseline: 2.3663x; 1.1523x over previous
//
#include <hip/hip_runtime.h>
#include <hip/hip_bf16.h>
#include <stdint.h>

// Problem constants (MultiHeadAttention: B=2, S=2048, H=16, Dk=Dv=64, Dm=1024)
#define BATCH 2
#define SEQ   2048
#define NH    16
#define DH    64
#define DM    1024
#define MR    (BATCH * SEQ)   // 4096 rows

typedef __bf16 bf16_t;
typedef bf16_t bf16x4 __attribute__((ext_vector_type(4)));
typedef bf16_t bf16x8 __attribute__((ext_vector_type(8)));
typedef float  f32x4  __attribute__((ext_vector_type(4)));

typedef const __attribute__((address_space(1))) void* gas_t;
typedef       __attribute__((address_space(3))) void* las_t;

__device__ __forceinline__ void gload16(const void* g, void* l) {
  __builtin_amdgcn_global_load_lds((gas_t)g, (las_t)l, 16, 0, 0);
}

__device__ __forceinline__ float fast_exp2(float x) {
#if __has_builtin(__builtin_amdgcn_exp2f)
  return __builtin_amdgcn_exp2f(x);
#else
  float r; asm volatile("v_exp_f32 %0, %1\n\ts_nop 1" : "=v"(r) : "v"(x)); return r;
#endif
}

// ---------------- fp32 -> bf16 elementwise, 3 tensors in one launch ------------
__global__ __launch_bounds__(256) void cvt3_kernel(const float* __restrict__ x0,
                                                   const float* __restrict__ x1,
                                                   const float* __restrict__ x2,
                                                   bf16_t* __restrict__ y0,
                                                   bf16_t* __restrict__ y1,
                                                   bf16_t* __restrict__ y2, int n) {
  const int z = blockIdx.y;
  const float* x = z == 0 ? x0 : (z == 1 ? x1 : x2);
  bf16_t*      y = z == 0 ? y0 : (z == 1 ? y1 : y2);
  int i = (blockIdx.x * 256 + threadIdx.x) * 8;
  if (i + 8 <= n) {
    float4 a = *(const float4*)(x + i);
    float4 b = *(const float4*)(x + i + 4);
    bf16x8 o;
    o[0] = (bf16_t)a.x; o[1] = (bf16_t)a.y; o[2] = (bf16_t)a.z; o[3] = (bf16_t)a.w;
    o[4] = (bf16_t)b.x; o[5] = (bf16_t)b.y; o[6] = (bf16_t)b.z; o[7] = (bf16_t)b.w;
    *(bf16x8*)(y + i) = o;
  }
}

// ---------------- W (KxN f32) -> Wt (NxK bf16), 4 weights in one launch --------
__global__ __launch_bounds__(256) void wtrans4_kernel(const float* __restrict__ W0,
                                                      const float* __restrict__ W1,
                                                      const float* __restrict__ W2,
                                                      const float* __restrict__ W3,
                                                      bf16_t* __restrict__ T0,
                                                      bf16_t* __restrict__ T1,
                                                      bf16_t* __restrict__ T2,
                                                      bf16_t* __restrict__ T3) {
  const int z = blockIdx.z;
  const float* W = z == 0 ? W0 : (z == 1 ? W1 : (z == 2 ? W2 : W3));
  bf16_t*     Wt = z == 0 ? T0 : (z == 1 ? T1 : (z == 2 ? T2 : T3));
  __shared__ bf16_t t[64][65];
  const int c0 = blockIdx.x * 64, r0 = blockIdx.y * 64;
  const int tid = threadIdx.x;
  const int r = tid >> 2, cc = (tid & 3) * 16;
  const float* src = W + (size_t)(r0 + r) * DM + c0 + cc;
#pragma unroll
  for (int i = 0; i < 16; ++i) t[r][cc + i] = (bf16_t)src[i];
  __syncthreads();
  bf16_t* dst = Wt + (size_t)(c0 + r) * DM + r0 + cc;
#pragma unroll
  for (int i = 0; i < 16; ++i) dst[i] = t[cc + i][r];
}

// ---------------- v (MR x DM) -> vT (per (b,h): DH x SEQ) ----------------
__global__ __launch_bounds__(256) void vtrans_kernel(const bf16_t* __restrict__ v,
                                                     bf16_t* __restrict__ vT) {
  __shared__ bf16_t t[64][65];
  const int s0 = blockIdx.x * 64;
  const int h = blockIdx.y, b = blockIdx.z;
  const int tid = threadIdx.x;
  const int r = tid >> 2, cc = (tid & 3) * 16;
  const bf16_t* src = v + (size_t)(b * SEQ + s0 + r) * DM + h * DH + cc;
#pragma unroll
  for (int i = 0; i < 16; ++i) t[r][cc + i] = src[i];
  __syncthreads();
  bf16_t* dst = vT + (size_t)((b * NH + h) * DH + r) * SEQ + s0 + cc;
#pragma unroll
  for (int i = 0; i < 16; ++i) dst[i] = t[cc + i][r];
}

// -------- fused Q/K/V projection GEMM: 128x128 tile, grid (32,8,3) = 768 blocks
// 3 blocks/CU -> cross-block overlap of the vmcnt(0)+barrier drain (m114).
__global__ __launch_bounds__(256) void gemm3_kernel(
    const bf16_t* __restrict__ A0, const bf16_t* __restrict__ A1,
    const bf16_t* __restrict__ A2,
    const bf16_t* __restrict__ B0, const bf16_t* __restrict__ B1,
    const bf16_t* __restrict__ B2,
    const float* __restrict__ bi0, const float* __restrict__ bi1,
    const float* __restrict__ bi2,
    float s0, float s1, float s2,
    bf16_t* __restrict__ C0, bf16_t* __restrict__ C1, bf16_t* __restrict__ C2) {
  const int z = blockIdx.z;
  const bf16_t* A    = z == 0 ? A0 : (z == 1 ? A1 : A2);
  const bf16_t* Bt   = z == 0 ? B0 : (z == 1 ? B1 : B2);
  const float*  bias = z == 0 ? bi0 : (z == 1 ? bi1 : bi2);
  const float   scale = z == 0 ? s0 : (z == 1 ? s1 : s2);
  bf16_t*       C    = z == 0 ? C0 : (z == 1 ? C1 : C2);
  const int K = DM, N = DM;

  __shared__ __attribute__((aligned(16))) bf16_t As[128 * 64];
  __shared__ __attribute__((aligned(16))) bf16_t Bs[128 * 64];
  const int m0 = blockIdx.x * 128, n0 = blockIdx.y * 128;
  const int tid = threadIdx.x;
  const int wave = tid >> 6, lane = tid & 63;
  const int lm = lane & 15, lg = lane >> 4;
  const int wr = wave >> 1, wc = wave & 1;
  f32x4 acc[4][4];
#pragma unroll
  for (int a = 0; a < 4; ++a)
#pragma unroll
    for (int bb = 0; bb < 4; ++bb) acc[a][bb] = (f32x4){0.f, 0.f, 0.f, 0.f};

  for (int k0 = 0; k0 < K; k0 += 64) {
    __syncthreads();
#pragma unroll
    for (int i = 0; i < 4; ++i) {
      const int c = tid + i * 256;
      const int row = c >> 3, j = c & 7, js = j ^ (row & 7);
      gload16(A  + (size_t)(m0 + row) * K + k0 + js * 8,
              As + (size_t)(wave * 64 + i * 256) * 8);
      gload16(Bt + (size_t)(n0 + row) * K + k0 + js * 8,
              Bs + (size_t)(wave * 64 + i * 256) * 8);
    }
    asm volatile("s_waitcnt vmcnt(0)" ::: "memory");
    __syncthreads();
#pragma unroll
    for (int kk = 0; kk < 2; ++kk) {
      bf16x8 af[4], bfr[4];
#pragma unroll
      for (int t = 0; t < 4; ++t) {
        const int ra = wr * 64 + t * 16 + lm;
        af[t] = *(const bf16x8*)((const char*)As + ra * 128 +
                                 ((kk * 64 + lg * 16) ^ ((ra & 7) << 4)));
        const int rb = wc * 64 + t * 16 + lm;
        bfr[t] = *(const bf16x8*)((const char*)Bs + rb * 128 +
                                  ((kk * 64 + lg * 16) ^ ((rb & 7) << 4)));
      }
      __builtin_amdgcn_s_setprio(1);
#pragma unroll
      for (int mf = 0; mf < 4; ++mf)
#pragma unroll
        for (int nf = 0; nf < 4; ++nf)
          acc[mf][nf] = __builtin_amdgcn_mfma_f32_16x16x32_bf16(af[mf], bfr[nf],
                                                                acc[mf][nf], 0, 0, 0);
      __builtin_amdgcn_s_setprio(0);
    }
  }
#pragma unroll
  for (int mf = 0; mf < 4; ++mf)
#pragma unroll
    for (int nf = 0; nf < 4; ++nf) {
      const int col = n0 + wc * 64 + nf * 16 + lm;
      const float bv = bias[col];
#pragma unroll
      for (int i = 0; i < 4; ++i) {
        const int row = m0 + wr * 64 + mf * 16 + lg * 4 + i;
        C[(size_t)row * N + col] = (bf16_t)((acc[mf][nf][i] + bv) * scale);
      }
    }
}

// ---------------- GEMM: C(MxN) = (A(MxK) @ Bt(NxK)^T + bias) * scale -----------
// 64x128 tile (512 blocks = 2/CU), used for the output projection (f32 out).
template <int OUT_BF16>
__global__ __launch_bounds__(256) void gemm_kernel(const bf16_t* __restrict__ A,
                                                   const bf16_t* __restrict__ Bt,
                                                   const float* __restrict__ bias,
                                                   float scale,
                                                   void* __restrict__ Cv,
                                                   int K, int N) {
  __shared__ __attribute__((aligned(16))) bf16_t As[64 * 64];    // 8 KB
  __shared__ __attribute__((aligned(16))) bf16_t Bs[128 * 64];   // 16 KB
  const int m0 = blockIdx.x * 64, n0 = blockIdx.y * 128;
  const int tid = threadIdx.x;
  const int wave = tid >> 6, lane = tid & 63;
  const int lm = lane & 15, lg = lane >> 4;
  const int wr = wave >> 1, wc = wave & 1;
  f32x4 acc[2][4];
#pragma unroll
  for (int a = 0; a < 2; ++a)
#pragma unroll
    for (int bb = 0; bb < 4; ++bb) acc[a][bb] = (f32x4){0.f, 0.f, 0.f, 0.f};

  for (int k0 = 0; k0 < K; k0 += 64) {
    __syncthreads();
#pragma unroll
    for (int i = 0; i < 2; ++i) {            // A: 512 chunks
      const int c = tid + i * 256;
      const int row = c >> 3, j = c & 7, js = j ^ (row & 7);
      gload16(A + (size_t)(m0 + row) * K + k0 + js * 8,
              As + (size_t)(wave * 64 + i * 256) * 8);
    }
#pragma unroll
    for (int i = 0; i < 4; ++i) {            // B: 1024 chunks
      const int c = tid + i * 256;
      const int row = c >> 3, j = c & 7, js = j ^ (row & 7);
      gload16(Bt + (size_t)(n0 + row) * K + k0 + js * 8,
              Bs + (size_t)(wave * 64 + i * 256) * 8);
    }
    asm volatile("s_waitcnt vmcnt(0)" ::: "memory");
    __syncthreads();
#pragma unroll
    for (int kk = 0; kk < 2; ++kk) {
      bf16x8 af[2], bfr[4];
#pragma unroll
      for (int t = 0; t < 2; ++t) {
        const int ra = wr * 32 + t * 16 + lm;
        af[t] = *(const bf16x8*)((const char*)As + ra * 128 +
                                 ((kk * 64 + lg * 16) ^ ((ra & 7) << 4)));
      }
#pragma unroll
      for (int t = 0; t < 4; ++t) {
        const int rb = wc * 64 + t * 16 + lm;
        bfr[t] = *(const bf16x8*)((const char*)Bs + rb * 128 +
                                  ((kk * 64 + lg * 16) ^ ((rb & 7) << 4)));
      }
      __builtin_amdgcn_s_setprio(1);
#pragma unroll
      for (int mf = 0; mf < 2; ++mf)
#pragma unroll
        for (int nf = 0; nf < 4; ++nf)
          acc[mf][nf] = __builtin_amdgcn_mfma_f32_16x16x32_bf16(af[mf], bfr[nf],
                                                                acc[mf][nf], 0, 0, 0);
      __builtin_amdgcn_s_setprio(0);
    }
  }
#pragma unroll
  for (int mf = 0; mf < 2; ++mf)
#pragma unroll
    for (int nf = 0; nf < 4; ++nf) {
      const int col = n0 + wc * 64 + nf * 16 + lm;
      const float bv = bias[col];
#pragma unroll
      for (int i = 0; i < 4; ++i) {
        const int row = m0 + wr * 32 + mf * 16 + lg * 4 + i;
        const float val = (acc[mf][nf][i] + bv) * scale;
        if (OUT_BF16) ((bf16_t*)Cv)[(size_t)row * N + col] = (bf16_t)val;
        else          ((float*)Cv)[(size_t)row * N + col] = val;
      }
    }
}

// ---------------- flash attention v3.1: staged K/V + swapped-QK softmax --------
// Grid 512 (XCD-swizzled), 8 waves x 16 q-rows. Double-buffered LDS tiles,
// counted vmcnt(2), raw s_barrier. + setprio around MFMA, defer-max (THR=8).
__global__ __launch_bounds__(512, 4) void flash_kernel(const bf16_t* __restrict__ q,
                                                       const bf16_t* __restrict__ k,
                                                       const bf16_t* __restrict__ vT,
                                                       bf16_t* __restrict__ o) {
  __shared__ __attribute__((aligned(16))) bf16_t Ks[2][64 * 64];   // 16 KB
  __shared__ __attribute__((aligned(16))) bf16_t Vs[2][64 * 64];   // 16 KB [d][k]
  __shared__ __attribute__((aligned(16))) bf16_t Ps[8][16 * 64];   // 16 KB
  const int wg = blockIdx.x;
  const int swz = (wg & 7) * 64 + (wg >> 3);     // 512 wgs, 64/XCD
  const int qt = swz & 15, h = (swz >> 4) & 15, b = swz >> 8;
  const int tid = threadIdx.x;
  const int wave = tid >> 6, lane = tid & 63;
  const int lm = lane & 15, lg = lane >> 4;
  char* PsW = (char*)(&Ps[wave][0]);

  const bf16_t* qb = q + (size_t)(b * SEQ + qt * 128 + wave * 16) * DM + h * DH;
  const int srow = tid >> 3, sjs = (tid & 7) ^ (srow & 7);
  const bf16_t* ksrc = k + (size_t)b * SEQ * DM + h * DH + (size_t)srow * DM + sjs * 8;
  const bf16_t* vsrc = vT + (size_t)(b * NH + h) * DH * SEQ + (size_t)srow * SEQ + sjs * 8;
  bf16_t* kdst0 = &Ks[0][wave * 512];
  bf16_t* kdst1 = &Ks[1][wave * 512];
  bf16_t* vdst0 = &Vs[0][wave * 512];
  bf16_t* vdst1 = &Vs[1][wave * 512];

  bf16x8 qf[2];
#pragma unroll
  for (int kk = 0; kk < 2; ++kk)
    qf[kk] = *(const bf16x8*)(qb + (size_t)lm * DM + kk * 32 + lg * 8);

  f32x4 acc[4];
#pragma unroll
  for (int nf = 0; nf < 4; ++nf) acc[nf] = (f32x4){0.f, 0.f, 0.f, 0.f};
  float mrun = -1e30f, lrun = 0.f;

  gload16(ksrc, kdst0);
  gload16(vsrc, vdst0);

  const int NT = SEQ / 64;  // 32
  for (int t = 0; t < NT; ++t) {
    const int cur = t & 1;
    asm volatile("" ::: "memory");
    __builtin_amdgcn_s_barrier();        // all waves done reading buf[cur^1]
    if (t + 1 < NT) {
      gload16(ksrc + (size_t)(t + 1) * 64 * DM, cur ? kdst0 : kdst1);
      gload16(vsrc + (t + 1) * 64,              cur ? vdst0 : vdst1);
      asm volatile("s_waitcnt vmcnt(2)" ::: "memory");   // tile t done; t+1 in flight
    } else {
      asm volatile("s_waitcnt vmcnt(0)" ::: "memory");
    }
    __builtin_amdgcn_s_barrier();        // tile t visible to all waves
    asm volatile("" ::: "memory");

    const char* Kb_ = (const char*)&Ks[cur][0];
    const char* Vb_ = (const char*)&Vs[cur][0];

    // ---- swapped QK^T: lane (lm,lg) holds S[k=nf*16+lg*4+i][q=lm] ----
    bf16x8 kf[2][4];
#pragma unroll
    for (int kk = 0; kk < 2; ++kk)
#pragma unroll
      for (int nf = 0; nf < 4; ++nf) {
        const int row = nf * 16 + lm;
        kf[kk][nf] = *(const bf16x8*)(Kb_ + row * 128 +
                                      ((kk * 64 + lg * 16) ^ ((row & 7) << 4)));
      }
    f32x4 sc[4];
#pragma unroll
    for (int nf = 0; nf < 4; ++nf) sc[nf] = (f32x4){0.f, 0.f, 0.f, 0.f};
    __builtin_amdgcn_s_setprio(1);
#pragma unroll
    for (int kk = 0; kk < 2; ++kk)
#pragma unroll
      for (int nf = 0; nf < 4; ++nf)
        sc[nf] = __builtin_amdgcn_mfma_f32_16x16x32_bf16(kf[kk][nf], qf[kk],
                                                         sc[nf], 0, 0, 0);
    __builtin_amdgcn_s_setprio(0);

    // ---- lane-local online softmax with defer-max (THR=8) ----
    float ml = fmaxf(
        fmaxf(fmaxf(fmaxf(sc[0][0], sc[0][1]), fmaxf(sc[0][2], sc[0][3])),
              fmaxf(fmaxf(sc[1][0], sc[1][1]), fmaxf(sc[1][2], sc[1][3]))),
        fmaxf(fmaxf(fmaxf(sc[2][0], sc[2][1]), fmaxf(sc[2][2], sc[2][3])),
              fmaxf(fmaxf(sc[3][0], sc[3][1]), fmaxf(sc[3][2], sc[3][3]))));
    ml = fmaxf(ml, __shfl_xor(ml, 16));
    ml = fmaxf(ml, __shfl_xor(ml, 32));
    const bool defer = __all(ml - mrun <= 8.0f);
    const float mn = defer ? mrun : fmaxf(mrun, ml);
#pragma unroll
    for (int nf = 0; nf < 4; ++nf)
#pragma unroll
      for (int i = 0; i < 4; ++i) sc[nf][i] = fast_exp2(sc[nf][i] - mn);
    float s = ((sc[0][0] + sc[0][1]) + (sc[0][2] + sc[0][3])) +
              ((sc[1][0] + sc[1][1]) + (sc[1][2] + sc[1][3])) +
              ((sc[2][0] + sc[2][1]) + (sc[2][2] + sc[2][3])) +
              ((sc[3][0] + sc[3][1]) + (sc[3][2] + sc[3][3]));
    s += __shfl_xor(s, 16);
    s += __shfl_xor(s, 32);
    if (defer) {
      lrun += s;
    } else {
      const float alpha = fast_exp2(mrun - mn);
      mrun = mn;
      lrun = lrun * alpha + s;
      float ai[4];
#pragma unroll
      for (int i = 0; i < 4; ++i) ai[i] = __shfl(alpha, (lane & 48) | (lg * 4 + i));
#pragma unroll
      for (int nf = 0; nf < 4; ++nf)
#pragma unroll
        for (int i = 0; i < 4; ++i) acc[nf][i] *= ai[i];
    }

    // ---- P -> per-wave LDS (row = q = lm) ----
#pragma unroll
    for (int nf = 0; nf < 4; ++nf) {
      bf16x4 pw;
      pw[0] = (bf16_t)sc[nf][0]; pw[1] = (bf16_t)sc[nf][1];
      pw[2] = (bf16_t)sc[nf][2]; pw[3] = (bf16_t)sc[nf][3];
      *(bf16x4*)(PsW + lm * 128 + ((nf * 32 + lg * 8) ^ ((lm & 7) << 4))) = pw;
    }

    // ---- PV: acc[nf] += P(16q x 64k) @ V(64k x 16d-block nf) ----
#pragma unroll
    for (int kk = 0; kk < 2; ++kk) {
      bf16x8 pf = *(const bf16x8*)(PsW + lm * 128 +
                                   ((kk * 64 + lg * 16) ^ ((lm & 7) << 4)));
      bf16x8 vf[4];
#pragma unroll
      for (int nf = 0; nf < 4; ++nf) {
        const int row = nf * 16 + lm;    // d-row in Vs
        vf[nf] = *(const bf16x8*)(Vb_ + row * 128 +
                                  ((kk * 64 + lg * 16) ^ ((row & 7) << 4)));
      }
      __builtin_amdgcn_s_setprio(1);
#pragma unroll
      for (int nf = 0; nf < 4; ++nf)
        acc[nf] = __builtin_amdgcn_mfma_f32_16x16x32_bf16(pf, vf[nf],
                                                          acc[nf], 0, 0, 0);
      __builtin_amdgcn_s_setprio(0);
    }
  }

  // ---- epilogue: O /= l ----
  const float inv = __builtin_amdgcn_rcpf(lrun);
  float li[4];
#pragma unroll
  for (int i = 0; i < 4; ++i) li[i] = __shfl(inv, (lane & 48) | (lg * 4 + i));
#pragma unroll
  for (int i = 0; i < 4; ++i) {
    const int row = b * SEQ + qt * 128 + wave * 16 + lg * 4 + i;
#pragma unroll
    for (int nf = 0; nf < 4; ++nf) {
      const int col = h * DH + nf * 16 + lm;
      o[(size_t)row * DM + col] = (bf16_t)(acc[nf][i] * li[i]);
    }
  }
}

extern "C" void kernel_launch(void* const* d_in, const int* in_sizes, int n_in,
                              void* d_out, int out_size, void* d_ws, size_t ws_size,
                              hipStream_t stream) {
  (void)in_sizes; (void)n_in; (void)out_size; (void)ws_size;
  const float* Q  = (const float*)d_in[0];
  const float* Kx = (const float*)d_in[1];
  const float* V  = (const float*)d_in[2];
  const float* WQ = (const float*)d_in[3];
  const float* bQ = (const float*)d_in[4];
  const float* WK = (const float*)d_in[5];
  const float* bK = (const float*)d_in[6];
  const float* WV = (const float*)d_in[7];
  const float* bV = (const float*)d_in[8];
  const float* WO = (const float*)d_in[9];
  const float* bO = (const float*)d_in[10];

  const size_t MS  = (size_t)MR * DM;   // 4M elements
  const size_t WSZ = (size_t)DM * DM;   // 1M elements
  bf16_t* ws  = (bf16_t*)d_ws;
  bf16_t* Qb  = ws;
  bf16_t* Kb  = Qb + MS;
  bf16_t* Vb  = Kb + MS;
  bf16_t* WQt = Vb + MS;
  bf16_t* WKt = WQt + WSZ;
  bf16_t* WVt = WKt + WSZ;
  bf16_t* WOt = WVt + WSZ;
  bf16_t* qp  = WOt + WSZ;
  bf16_t* kp  = qp + MS;
  bf16_t* vp  = kp + MS;
  bf16_t* vTb = Qb;   // alias: Qb dead after q projection
  bf16_t* ao  = Kb;   // alias: Kb dead after k projection

  // fold score scale and log2(e) into the q projection -> softmax uses exp2
  const float scale_q = 0.125f * 1.44269504088896340736f;

  cvt3_kernel<<<dim3((unsigned)(MS / 2048), 3), 256, 0, stream>>>(Q, Kx, V, Qb, Kb, Vb, (int)MS);
  wtrans4_kernel<<<dim3(16, 16, 4), 256, 0, stream>>>(WQ, WK, WV, WO, WQt, WKt, WVt, WOt);

  gemm3_kernel<<<dim3(32, 8, 3), 256, 0, stream>>>(Qb, Kb, Vb,
                                                   WQt, WKt, WVt,
                                                   bQ, bK, bV,
                                                   scale_q, 1.0f, 1.0f,
                                                   qp, kp, vp);

  vtrans_kernel<<<dim3(SEQ / 64, NH, BATCH), 256, 0, stream>>>(vp, vTb);
  flash_kernel<<<dim3(512), 512, 0, stream>>>(qp, kp, vTb, ao);
  gemm_kernel<0><<<dim3(MR / 64, DM / 128), 256, 0, stream>>>(ao, WOt, bO, 1.0f, d_out, DM, DM);
}